// Round 9
// baseline (131.052 us; speedup 1.0000x reference)
//
#include <hip/hip_runtime.h>
#include <hip/hip_bf16.h>

#define B_  1024
#define LA  529   // token positions -> conv channels
#define EE  100   // embedding dim -> conv steps
#define NF  16    // conv filters
#define NT  50    // conv output steps
#define NS  25    // pooled steps
#define NU  100   // LSTM units
#define NJ  400   // 4*NU
#define PF  8     // e-prefetch depth
#define NBB 16    // batches per block in kernel B

typedef float    f32x4v __attribute__((ext_vector_type(4)));
typedef short    s16x8  __attribute__((ext_vector_type(8)));
typedef _Float16 h2v    __attribute__((ext_vector_type(2)));
typedef _Float16 h16x8  __attribute__((ext_vector_type(8)));

__device__ __forceinline__ float leaky(float v) { return v >= 0.f ? v : 0.2f * v; }

__device__ __forceinline__ unsigned int pkh2(float x, float y) {
    auto p = __builtin_amdgcn_cvt_pkrtz(x, y);   // __fp16 ext_vector(2)
    return __builtin_bit_cast(unsigned int, p);
}
__device__ __forceinline__ unsigned short f2h(float x) {
    return __builtin_bit_cast(unsigned short, (_Float16)x);
}

__device__ __forceinline__ float fdot2h(unsigned int e, unsigned int w, float acc) {
#if __has_builtin(__builtin_amdgcn_fdot2)
    return __builtin_amdgcn_fdot2(__builtin_bit_cast(h2v, e),
                                  __builtin_bit_cast(h2v, w), acc, false);
#else
    h2v ev = __builtin_bit_cast(h2v, e), wv = __builtin_bit_cast(h2v, w);
    return acc + (float)ev.x * (float)wv.x + (float)ev.y * (float)wv.y;
#endif
}

// ---------------- Kernel P: fp32 -> fp16 conversion ----------------
__global__ __launch_bounds__(256) void prep_kernel(
    const float* __restrict__ emb,      // [V*E]
    const float* __restrict__ conv_w,   // [2][529][16]
    unsigned int* __restrict__ emb_h,   // [V*E/2] packed half2
    unsigned int* __restrict__ convw_h) // [529*16] packed (w0,w1)
{
    const int gid = blockIdx.x * 256 + threadIdx.x;
    const int stride = gridDim.x * 256;
    for (int i = gid; i < (15245 * 100) / 2; i += stride) {
        const float2 v = ((const float2*)emb)[i];
        emb_h[i] = pkh2(v.x, v.y);
    }
    for (int i = gid; i < LA * NF; i += stride)
        convw_h[i] = pkh2(conv_w[i], conv_w[LA * NF + i]);
}

// ---------------- Kernel A: gather + conv + relu + maxpool ----------------
// 1024 blocks x 256 threads; block = batch; wave w owns contiguous cols.
// fp16 table (L2-resident), weights in LDS, inner product via v_dot2_f32_f16.
__global__ __launch_bounds__(256) void conv_embed_kernel(
    const int*          __restrict__ tokens,
    const unsigned int* __restrict__ emb_h,   // [V][50] half2 rows
    const unsigned int* __restrict__ convw_h, // [529][16] (w0,w1) half2
    const float*        __restrict__ conv_b,
    float*              __restrict__ p_out)   // [B][25][16]
{
    __shared__ __align__(16) unsigned int smem[LA * NF];  // 33.9 KB (union)
    unsigned int* wlds = smem;
    float* part = (float*)smem;           // [4][50][16] after compute
    float* ylds = (float*)smem + 3200;    // [50][16]

    const int tid  = threadIdx.x;
    const int b    = blockIdx.x;
    const int lane = tid & 63;
    const int w    = __builtin_amdgcn_readfirstlane(tid >> 6);
    const int t    = lane < NT ? lane : (NT - 1);

    for (int i = tid; i < (LA * NF) / 4; i += 256)
        ((uint4*)smem)[i] = ((const uint4*)convw_h)[i];
    __syncthreads();

    const int cbase = w * 133;
    const int NC    = (w < 3) ? 133 : 130;
    const int* __restrict__ tokb = tokens + (size_t)b * LA + cbase;

    float acc[NF];
#pragma unroll
    for (int f = 0; f < NF; ++f) acc[f] = 0.f;

#define LOAD_E(dst, i_) do { \
    const int i2 = (i_); \
    const int ic = (i2 < NC) ? i2 : 0; \
    unsigned int v = emb_h[(size_t)tokb[ic] * 50 + t]; \
    if (i2 >= NC) v = 0u; \
    (dst) = v; } while (0)

    unsigned int ebuf[PF];
#pragma unroll
    for (int j = 0; j < PF; ++j) LOAD_E(ebuf[j], j);

    for (int ig = 0; ig < 136; ig += PF) {   // 17 groups cover i = 0..135 >= NC
        unsigned int enxt[PF];
#pragma unroll
        for (int j = 0; j < PF; ++j) LOAD_E(enxt[j], ig + PF + j);
#pragma unroll
        for (int j = 0; j < PF; ++j) {
            const int i  = ig + j;
            const int cc = cbase + ((i < NC) ? i : 0);  // padded cols have e=0
            const unsigned int* wp = wlds + cc * NF;
            unsigned int wv[NF];
#pragma unroll
            for (int q = 0; q < 4; ++q) ((uint4*)wv)[q] = ((const uint4*)wp)[q];
#pragma unroll
            for (int f = 0; f < NF; ++f) acc[f] = fdot2h(ebuf[j], wv[f], acc[f]);
        }
#pragma unroll
        for (int j = 0; j < PF; ++j) ebuf[j] = enxt[j];
    }
#undef LOAD_E

    __syncthreads();   // all waves done reading wlds; reuse as part buffer
    if (lane < NT) {
        float4* dst = (float4*)(part + (size_t)(w * NT + lane) * NF);
#pragma unroll
        for (int q = 0; q < 4; ++q) dst[q] = ((float4*)acc)[q];
    }
    __syncthreads();

    if (tid < 200) {
        const int tr = tid >> 2, fq = tid & 3;
        float4 s0 = ((float4*)(part + (0 * NT + tr) * NF))[fq];
        float4 s1 = ((float4*)(part + (1 * NT + tr) * NF))[fq];
        float4 s2 = ((float4*)(part + (2 * NT + tr) * NF))[fq];
        float4 s3 = ((float4*)(part + (3 * NT + tr) * NF))[fq];
        float4 cb = ((const float4*)conv_b)[fq];
        float4 y;
        y.x = fmaxf(s0.x + s1.x + s2.x + s3.x + cb.x, 0.f);
        y.y = fmaxf(s0.y + s1.y + s2.y + s3.y + cb.y, 0.f);
        y.z = fmaxf(s0.z + s1.z + s2.z + s3.z + cb.z, 0.f);
        y.w = fmaxf(s0.w + s1.w + s2.w + s3.w + cb.w, 0.f);
        ((float4*)(ylds + tr * NF))[fq] = y;
    }
    __syncthreads();

    for (int idx = tid; idx < NS * NF; idx += 256) {
        const int s = idx >> 4, f = idx & 15;
        p_out[(size_t)b * (NS * NF) + idx] =
            fmaxf(ylds[2 * s * NF + f], ylds[(2 * s + 1) * NF + f]);
    }
}

// ---------------- Kernel B: fp16 MFMA LSTM, weights in LDS ----------------
// 64 blocks x 512 threads, 16 batches/block. 28 j-tiles = 4 gates x 7 u-tiles
// (NU padded to 112). Wave w (0..6) owns tiles {g*7+w}: zi,zf,zg,zo for a
// (u,b) pair land in the same lane -> gates in-register, ONE barrier/step.
// B-fragments live in LDS in MFMA fragment layout (112 KB) and are re-read
// each step via conflict-free ds_read_b128 — immune to the register
// allocator's spill/remat of large stationary sets (rounds 3/7/8 failure).
__global__ __launch_bounds__(512) void lstm_mfma_kernel(
    const float* __restrict__ p_in,    // [B][25][16]
    const float* __restrict__ k_lstm,  // [16][400]
    const float* __restrict__ rk,      // [100][400]
    const float* __restrict__ b_lstm,  // [400]
    const float* __restrict__ w1,      // [100][64]
    const float* __restrict__ b1,      // [64]
    const float* __restrict__ w2,      // [64][3]
    const float* __restrict__ b2,      // [3]
    float*       __restrict__ out)     // [B][3]
{
    __shared__ __align__(16) unsigned short b_lds[28 * 2048];    // 112 KB
    __shared__ __align__(16) unsigned short a_lds[2][4][64][8];  // dbuf, 8 KB
    __shared__ float h_f32[NBB][NU];                             // 6.4 KB
    float* d_lds = (float*)&a_lds[0][0][0][0];   // overlay (4 KB, used after loop)

    const int tid  = threadIdx.x;
    const int lane = tid & 63;
    const int wid  = tid >> 6;
    const int b0   = blockIdx.x * NBB;

    // zero A-buffer (pad k=117..127 stays 0 forever)
    for (int i = tid; i < 2 * 4 * 64 * 8; i += 512) ((unsigned short*)a_lds)[i] = 0;

    // ---- stage B = W_aug in MFMA fragment layout ----
    // b_lds[t][c][l][e]: tile t = g*7+ut, col jl = ut*16+(l&15),
    // k = c*32 + (l>>4)*8 + e. W(k,j): rk | k_lstm | bias-row | 0-pad.
    for (int n = tid; n < 28 * 2048; n += 512) {
        const int t = n >> 11, c = (n >> 9) & 3, l = (n >> 3) & 63, e = n & 7;
        const int g = t / 7, ut = t - g * 7;
        const int jl = ut * 16 + (l & 15);
        const int k  = c * 32 + ((l >> 4) << 3) + e;
        float x = 0.f;
        if (jl < NU) {
            const int jg = g * NU + jl;
            if (k < NU)        x = rk[k * NJ + jg];
            else if (k < 116)  x = k_lstm[(k - NU) * NJ + jg];
            else if (k == 116) x = b_lstm[jg];
        }
        b_lds[n] = f2h(x);
    }

    const int col = lane & 15;
    const int jl  = (wid < 7 ? wid : 6) * 16 + col;   // unit 0..111
    const bool uvalid = (wid < 7) && (jl < NU);
    __syncthreads();   // zeroing + B staging complete

    // p(t=0) into buf 0; bias slot k=116 (fp16 1.0) into both buffers
    if (tid < 256) {
        const int pb = tid >> 4, pf = tid & 15;
        const float pv = p_in[(size_t)(b0 + pb) * (NS * NF) + pf];
        const int k = 100 + pf;
        a_lds[0][k >> 5][(((k >> 3) & 3) << 4) + pb][k & 7] = f2h(pv);
    }
    if (tid < NBB) {
        a_lds[0][3][32 + tid][4] = 0x3C00;
        a_lds[1][3][32 + tid][4] = 0x3C00;
    }
    float cst[4] = {0.f, 0.f, 0.f, 0.f};
    __syncthreads();

#pragma unroll 1
    for (int t = 0; t < NS; ++t) {
        const int cur = t & 1, nxt = cur ^ 1;
        if (wid == 7) {
            if (t + 1 < NS) {
#pragma unroll
                for (int r = 0; r < 4; ++r) {
                    const int idx = (tid - 448) + 64 * r;
                    const int pb = idx >> 4, pf = idx & 15;
                    const float pv =
                        p_in[(size_t)(b0 + pb) * (NS * NF) + (t + 1) * NF + pf];
                    const int k = 100 + pf;
                    a_lds[nxt][k >> 5][(((k >> 3) & 3) << 4) + pb][k & 7] = f2h(pv);
                }
            }
        } else {
            // A fragments (shared across the 4 gates)
            h16x8 ah[4];
#pragma unroll
            for (int c = 0; c < 4; ++c)
                ah[c] = __builtin_bit_cast(h16x8, ((const s16x8*)a_lds[cur][c])[lane]);
            // B fragments for this wave's 4 tiles (16 x ds_read_b128)
            h16x8 bf[4][4];
#pragma unroll
            for (int g = 0; g < 4; ++g) {
                const unsigned short* bp = b_lds + ((g * 7 + wid) * 4) * 512;
#pragma unroll
                for (int c = 0; c < 4; ++c)
                    bf[g][c] = __builtin_bit_cast(h16x8,
                        ((const s16x8*)(bp + c * 512))[lane]);
            }
            f32x4v acc[4];
#pragma unroll
            for (int g = 0; g < 4; ++g) {
                f32x4v z0 = {0.f, 0.f, 0.f, 0.f}, z1 = {0.f, 0.f, 0.f, 0.f};
                z0 = __builtin_amdgcn_mfma_f32_16x16x32_f16(ah[0], bf[g][0], z0, 0, 0, 0);
                z1 = __builtin_amdgcn_mfma_f32_16x16x32_f16(ah[1], bf[g][1], z1, 0, 0, 0);
                z0 = __builtin_amdgcn_mfma_f32_16x16x32_f16(ah[2], bf[g][2], z0, 0, 0, 0);
                z1 = __builtin_amdgcn_mfma_f32_16x16x32_f16(ah[3], bf[g][3], z1, 0, 0, 0);
                acc[g] = z0 + z1;
            }
            // in-register gates: lane owns unit jl, batches 4*(lane>>4)+q
            const int c_  = jl >> 5;
            const int lsb = ((jl >> 3) & 3) << 4;
            const int e_  = jl & 7;
#pragma unroll
            for (int q = 0; q < 4; ++q) {
                const float zi = acc[0][q], zf = acc[1][q];
                const float zg = acc[2][q], zo = acc[3][q];
                const float ig  = 1.f / (1.f + __expf(-zi));
                const float fg_ = 1.f / (1.f + __expf(-zf));
                const float og  = 1.f / (1.f + __expf(-zo));
                cst[q] = fg_ * cst[q] + ig * leaky(zg);
                const float h = og * leaky(cst[q]);
                if (uvalid) {
                    const int bb = ((lane >> 4) << 2) + q;
                    a_lds[nxt][c_][lsb + bb][e_] = f2h(h);
                    if (t == NS - 1) h_f32[bb][jl] = h;
                }
            }
        }
        __syncthreads();
    }

    // dense head: d = tanh(h @ w1 + b1), 1024 outputs / 512 threads
#pragma unroll
    for (int r = 0; r < 2; ++r) {
        const int o = tid + 512 * r;
        const int hb = o >> 6, m = o & 63;
        float a = b1[m];
#pragma unroll 4
        for (int u = 0; u < NU; ++u) a += h_f32[hb][u] * w1[u * 64 + m];
        d_lds[o] = tanhf(a);
    }
    __syncthreads();

    // logits + softmax (3 classes)
    if (tid < NBB) {
        float l0 = b2[0], l1 = b2[1], l2 = b2[2];
        for (int m = 0; m < 64; ++m) {
            const float d = d_lds[tid * 64 + m];
            l0 += d * w2[m * 3 + 0];
            l1 += d * w2[m * 3 + 1];
            l2 += d * w2[m * 3 + 2];
        }
        const float mx = fmaxf(l0, fmaxf(l1, l2));
        const float e0 = __expf(l0 - mx), e1 = __expf(l1 - mx), e2 = __expf(l2 - mx);
        const float inv = 1.f / (e0 + e1 + e2);
        out[(b0 + tid) * 3 + 0] = e0 * inv;
        out[(b0 + tid) * 3 + 1] = e1 * inv;
        out[(b0 + tid) * 3 + 2] = e2 * inv;
    }
}

extern "C" void kernel_launch(void* const* d_in, const int* in_sizes, int n_in,
                              void* d_out, int out_size, void* d_ws, size_t ws_size,
                              hipStream_t stream) {
    const int*   tokens = (const int*)  d_in[0];
    const float* emb    = (const float*)d_in[1];
    const float* conv_w = (const float*)d_in[2];
    const float* conv_b = (const float*)d_in[3];
    const float* k_lstm = (const float*)d_in[4];
    const float* rk     = (const float*)d_in[5];
    const float* b_lstm = (const float*)d_in[6];
    const float* w1     = (const float*)d_in[7];
    const float* b1     = (const float*)d_in[8];
    const float* w2     = (const float*)d_in[9];
    const float* b2     = (const float*)d_in[10];
    float* out = (float*)d_out;

    // ws layout (bytes): p[1024][25][16] f32 : [0, 1638400)
    //                    emb_h (half2)       : [1638400, 4687400) -> align 4687408
    //                    convw_h (half2)     : [4687408, 4721264)
    char* ws = (char*)d_ws;
    float*        p_ws    = (float*)ws;
    unsigned int* emb_h   = (unsigned int*)(ws + 1638400);
    unsigned int* convw_h = (unsigned int*)(ws + 4687408);

    prep_kernel<<<1024, 256, 0, stream>>>(emb, conv_w, emb_h, convw_h);
    conv_embed_kernel<<<B_, 256, 0, stream>>>(tokens, emb_h, convw_h, conv_b, p_ws);
    lstm_mfma_kernel<<<B_ / NBB, 512, 0, stream>>>(p_ws, k_lstm, rk, b_lstm,
                                                   w1, b1, w2, b2, out);
}

// Round 10
// 109.316 us; speedup vs baseline: 1.1988x; 1.1988x over previous
//
#include <hip/hip_runtime.h>
#include <hip/hip_bf16.h>

#define B_  1024
#define LA  529   // token positions -> conv channels
#define EE  100   // embedding dim -> conv steps
#define NF  16    // conv filters
#define NT  50    // conv output steps
#define NS  25    // pooled steps
#define NU  100   // LSTM units
#define NJ  400   // 4*NU
#define PF  8     // e-prefetch depth

typedef _Float16 h2v __attribute__((ext_vector_type(2)));

__device__ __forceinline__ float leaky(float v) { return v >= 0.f ? v : 0.2f * v; }

__device__ __forceinline__ unsigned int pkh2(float x, float y) {
    auto p = __builtin_amdgcn_cvt_pkrtz(x, y);   // __fp16 ext_vector(2)
    return __builtin_bit_cast(unsigned int, p);
}
__device__ __forceinline__ unsigned short f2h(float x) {
    return __builtin_bit_cast(unsigned short, (_Float16)x);
}

__device__ __forceinline__ float fdot2h(unsigned int e, unsigned int w, float acc) {
#if __has_builtin(__builtin_amdgcn_fdot2)
    return __builtin_amdgcn_fdot2(__builtin_bit_cast(h2v, e),
                                  __builtin_bit_cast(h2v, w), acc, false);
#else
    h2v ev = __builtin_bit_cast(h2v, e), wv = __builtin_bit_cast(h2v, w);
    return acc + (float)ev.x * (float)wv.x + (float)ev.y * (float)wv.y;
#endif
}

// ---------------- Kernel P: fp32 -> fp16 conversion ----------------
__global__ __launch_bounds__(256) void prep_kernel(
    const float* __restrict__ emb,      // [V*E]
    const float* __restrict__ conv_w,   // [2][529][16]
    unsigned int* __restrict__ emb_h,   // [V*E/2] packed half2
    unsigned int* __restrict__ convw_h) // [529*16] packed (w0,w1)
{
    const int gid = blockIdx.x * 256 + threadIdx.x;
    const int stride = gridDim.x * 256;
    for (int i = gid; i < (15245 * 100) / 2; i += stride) {
        const float2 v = ((const float2*)emb)[i];
        emb_h[i] = pkh2(v.x, v.y);
    }
    for (int i = gid; i < LA * NF; i += stride)
        convw_h[i] = pkh2(conv_w[i], conv_w[LA * NF + i]);
}

// ---------------- Kernel A: gather + conv + relu + maxpool ----------------
// (unchanged from round 9: fp16 table, LDS weights, v_dot2_f32_f16)
__global__ __launch_bounds__(256) void conv_embed_kernel(
    const int*          __restrict__ tokens,
    const unsigned int* __restrict__ emb_h,   // [V][50] half2 rows
    const unsigned int* __restrict__ convw_h, // [529][16] (w0,w1) half2
    const float*        __restrict__ conv_b,
    float*              __restrict__ p_out)   // [B][25][16]
{
    __shared__ __align__(16) unsigned int smem[LA * NF];  // 33.9 KB (union)
    unsigned int* wlds = smem;
    float* part = (float*)smem;           // [4][50][16] after compute
    float* ylds = (float*)smem + 3200;    // [50][16]

    const int tid  = threadIdx.x;
    const int b    = blockIdx.x;
    const int lane = tid & 63;
    const int w    = __builtin_amdgcn_readfirstlane(tid >> 6);
    const int t    = lane < NT ? lane : (NT - 1);

    for (int i = tid; i < (LA * NF) / 4; i += 256)
        ((uint4*)smem)[i] = ((const uint4*)convw_h)[i];
    __syncthreads();

    const int cbase = w * 133;
    const int NC    = (w < 3) ? 133 : 130;
    const int* __restrict__ tokb = tokens + (size_t)b * LA + cbase;

    float acc[NF];
#pragma unroll
    for (int f = 0; f < NF; ++f) acc[f] = 0.f;

#define LOAD_E(dst, i_) do { \
    const int i2 = (i_); \
    const int ic = (i2 < NC) ? i2 : 0; \
    unsigned int v = emb_h[(size_t)tokb[ic] * 50 + t]; \
    if (i2 >= NC) v = 0u; \
    (dst) = v; } while (0)

    unsigned int ebuf[PF];
#pragma unroll
    for (int j = 0; j < PF; ++j) LOAD_E(ebuf[j], j);

    for (int ig = 0; ig < 136; ig += PF) {
        unsigned int enxt[PF];
#pragma unroll
        for (int j = 0; j < PF; ++j) LOAD_E(enxt[j], ig + PF + j);
#pragma unroll
        for (int j = 0; j < PF; ++j) {
            const int i  = ig + j;
            const int cc = cbase + ((i < NC) ? i : 0);
            const unsigned int* wp = wlds + cc * NF;
            unsigned int wv[NF];
#pragma unroll
            for (int q = 0; q < 4; ++q) ((uint4*)wv)[q] = ((const uint4*)wp)[q];
#pragma unroll
            for (int f = 0; f < NF; ++f) acc[f] = fdot2h(ebuf[j], wv[f], acc[f]);
        }
#pragma unroll
        for (int j = 0; j < PF; ++j) ebuf[j] = enxt[j];
    }
#undef LOAD_E

    __syncthreads();
    if (lane < NT) {
        float4* dst = (float4*)(part + (size_t)(w * NT + lane) * NF);
#pragma unroll
        for (int q = 0; q < 4; ++q) dst[q] = ((float4*)acc)[q];
    }
    __syncthreads();

    if (tid < 200) {
        const int tr = tid >> 2, fq = tid & 3;
        float4 s0 = ((float4*)(part + (0 * NT + tr) * NF))[fq];
        float4 s1 = ((float4*)(part + (1 * NT + tr) * NF))[fq];
        float4 s2 = ((float4*)(part + (2 * NT + tr) * NF))[fq];
        float4 s3 = ((float4*)(part + (3 * NT + tr) * NF))[fq];
        float4 cb = ((const float4*)conv_b)[fq];
        float4 y;
        y.x = fmaxf(s0.x + s1.x + s2.x + s3.x + cb.x, 0.f);
        y.y = fmaxf(s0.y + s1.y + s2.y + s3.y + cb.y, 0.f);
        y.z = fmaxf(s0.z + s1.z + s2.z + s3.z + cb.z, 0.f);
        y.w = fmaxf(s0.w + s1.w + s2.w + s3.w + cb.w, 0.f);
        ((float4*)(ylds + tr * NF))[fq] = y;
    }
    __syncthreads();

    for (int idx = tid; idx < NS * NF; idx += 256) {
        const int s = idx >> 4, f = idx & 15;
        p_out[(size_t)b * (NS * NF) + idx] =
            fmaxf(ylds[2 * s * NF + f], ylds[(2 * s + 1) * NF + f]);
    }
}

// ---------------- Kernel B: register-dot2 LSTM + head --------------------
// 512 blocks x 448 threads, 2 batches/block (co-residency: 2-3 blocks/CU).
// Thread j<400 holds W_aug[:,j] as 58 packed-fp16 pairs (58 VGPR) -> z[j]
// for both batches via v_dot2_f32_f16 with h/p broadcast-read from LDS as
// uint4. Gates fp32 on threads 0..199. All p staged in LDS: zero global
// traffic in the 25-step loop. Tiny LDS (~7 KB) + ~100 VGPR -> blocks
// overlap each step's latency chain (the round-7/8/9 wall).
__global__ __launch_bounds__(448) void lstm_reg_kernel(
    const float* __restrict__ p_in,    // [B][25][16]
    const float* __restrict__ k_lstm,  // [16][400]
    const float* __restrict__ rk,      // [100][400]
    const float* __restrict__ b_lstm,  // [400]
    const float* __restrict__ w1,      // [100][64]
    const float* __restrict__ b1,      // [64]
    const float* __restrict__ w2,      // [64][3]
    const float* __restrict__ b2,      // [3]
    float*       __restrict__ out)     // [B][3]
{
    __shared__ __align__(16) unsigned int h2[2][64];      // pairs: 0-49 h, 50-57 p, 58+ zero
    __shared__ __align__(16) unsigned int p2[2][NS][8];   // p pairs per step, 1.6 KB
    __shared__ float zb[2][NJ];                           // 3.2 KB
    __shared__ float hf[2][NU];                           // final h
    __shared__ float db[2][64];
    __shared__ float lgl[2][4];

    const int tid = threadIdx.x;
    const int b0  = blockIdx.x * 2;
    const int j   = tid < NJ ? tid : 0;

    // ---- W columns into registers: 60 packed pairs (58 real + 2 zero) ----
    unsigned int wreg[60];
#pragma unroll
    for (int q = 0; q < 50; ++q)
        wreg[q] = pkh2(rk[(2 * q) * NJ + j], rk[(2 * q + 1) * NJ + j]);
#pragma unroll
    for (int q = 50; q < 58; ++q)
        wreg[q] = pkh2(k_lstm[(2 * (q - 50)) * NJ + j],
                       k_lstm[(2 * (q - 50) + 1) * NJ + j]);
    wreg[58] = 0u; wreg[59] = 0u;
    const float bias_j = b_lstm[j];

    // ---- stage p pairs + init h2 ----
    for (int i = tid; i < 2 * NS * 8; i += 448) {
        const int bb = i / (NS * 8), r = i % (NS * 8), tt = r >> 3, s = r & 7;
        const float* pp = p_in + (size_t)(b0 + bb) * (NS * NF) + tt * NF + 2 * s;
        p2[bb][tt][s] = pkh2(pp[0], pp[1]);
    }
    if (tid < 128) {                      // h2 init: h=0, p(t=0), zero pad
        const int bb = tid >> 6, s = tid & 63;
        unsigned int v = 0u;
        if (s >= 50 && s < 58) {
            const float* pp = p_in + (size_t)(b0 + bb) * (NS * NF) + 2 * (s - 50);
            v = pkh2(pp[0], pp[1]);
        }
        h2[bb][s] = v;
    }
    float cst = 0.f;
    const int tb = (tid >= NU) ? 1 : 0;   // gate threads (tid < 200)
    const int tu = tid - tb * NU;
    __syncthreads();

#pragma unroll 1
    for (int t = 0; t < NS; ++t) {
        if (tid < NJ) {
            float a0 = bias_j, a1 = 0.f, c0 = bias_j, c1 = 0.f;
#pragma unroll
            for (int q4 = 0; q4 < 15; q4 += 1) {
                const uint4 h0 = ((const uint4*)h2[0])[q4];
                const uint4 h1 = ((const uint4*)h2[1])[q4];
                a0 = fdot2h(h0.x, wreg[4 * q4 + 0], a0);
                a1 = fdot2h(h0.y, wreg[4 * q4 + 1], a1);
                a0 = fdot2h(h0.z, wreg[4 * q4 + 2], a0);
                a1 = fdot2h(h0.w, wreg[4 * q4 + 3], a1);
                c0 = fdot2h(h1.x, wreg[4 * q4 + 0], c0);
                c1 = fdot2h(h1.y, wreg[4 * q4 + 1], c1);
                c0 = fdot2h(h1.z, wreg[4 * q4 + 2], c0);
                c1 = fdot2h(h1.w, wreg[4 * q4 + 3], c1);
            }
            zb[0][tid] = a0 + a1;
            zb[1][tid] = c0 + c1;
        }
        __syncthreads();
        if (tid < 2 * NU) {
            const float zi = zb[tb][tu];
            const float zf = zb[tb][tu + 100];
            const float zg = zb[tb][tu + 200];
            const float zo = zb[tb][tu + 300];
            const float ig  = 1.f / (1.f + __expf(-zi));
            const float fg_ = 1.f / (1.f + __expf(-zf));
            const float og  = 1.f / (1.f + __expf(-zo));
            cst = fg_ * cst + ig * leaky(zg);
            const float h = og * leaky(cst);
            ((unsigned short*)h2[tb])[tu] = f2h(h);   // byte offset 2*tu
            if (t == NS - 1) hf[tb][tu] = h;
        } else if (tid < 216 && t + 1 < NS) {         // copy p(t+1) pairs
            const int bb = (tid - 200) >> 3, s = (tid - 200) & 7;
            h2[bb][50 + s] = p2[bb][t + 1][s];
        }
        __syncthreads();
    }

    // dense head: d = tanh(h @ w1 + b1)
    if (tid < 128) {
        const int hb = tid >> 6, m = tid & 63;
        float a = b1[m];
#pragma unroll 4
        for (int u = 0; u < NU; ++u) a += hf[hb][u] * w1[u * 64 + m];
        db[hb][m] = tanhf(a);
    }
    __syncthreads();
    if (tid < 6) {
        const int bb = tid >> 1 == 0 ? tid / 3 : tid / 3;   // bb = tid/3
        const int cls = tid - (tid / 3) * 3;
        float l = b2[cls];
        for (int m = 0; m < 64; ++m) l += db[tid / 3][m] * w2[m * 3 + cls];
        lgl[tid / 3][cls] = l;
        (void)bb;
    }
    __syncthreads();
    if (tid < 2) {
        const float l0 = lgl[tid][0], l1 = lgl[tid][1], l2 = lgl[tid][2];
        const float mx = fmaxf(l0, fmaxf(l1, l2));
        const float e0 = __expf(l0 - mx), e1 = __expf(l1 - mx), e2 = __expf(l2 - mx);
        const float inv = 1.f / (e0 + e1 + e2);
        out[(b0 + tid) * 3 + 0] = e0 * inv;
        out[(b0 + tid) * 3 + 1] = e1 * inv;
        out[(b0 + tid) * 3 + 2] = e2 * inv;
    }
}

extern "C" void kernel_launch(void* const* d_in, const int* in_sizes, int n_in,
                              void* d_out, int out_size, void* d_ws, size_t ws_size,
                              hipStream_t stream) {
    const int*   tokens = (const int*)  d_in[0];
    const float* emb    = (const float*)d_in[1];
    const float* conv_w = (const float*)d_in[2];
    const float* conv_b = (const float*)d_in[3];
    const float* k_lstm = (const float*)d_in[4];
    const float* rk     = (const float*)d_in[5];
    const float* b_lstm = (const float*)d_in[6];
    const float* w1     = (const float*)d_in[7];
    const float* b1     = (const float*)d_in[8];
    const float* w2     = (const float*)d_in[9];
    const float* b2     = (const float*)d_in[10];
    float* out = (float*)d_out;

    // ws layout (bytes): p[1024][25][16] f32 : [0, 1638400)
    //                    emb_h (half2)       : [1638400, 4687400) -> align 4687408
    //                    convw_h (half2)     : [4687408, 4721264)
    char* ws = (char*)d_ws;
    float*        p_ws    = (float*)ws;
    unsigned int* emb_h   = (unsigned int*)(ws + 1638400);
    unsigned int* convw_h = (unsigned int*)(ws + 4687408);

    prep_kernel<<<1024, 256, 0, stream>>>(emb, conv_w, emb_h, convw_h);
    conv_embed_kernel<<<B_, 256, 0, stream>>>(tokens, emb_h, convw_h, conv_b, p_ws);
    lstm_reg_kernel<<<B_ / 2, 448, 0, stream>>>(p_ws, k_lstm, rk, b_lstm,
                                                w1, b1, w2, b2, out);
}